// Round 3
// baseline (411.398 us; speedup 1.0000x reference)
//
#include <hip/hip_runtime.h>
#include <hip/hip_bf16.h>
#include <stdint.h>
#include <math.h>

typedef __bf16 bf16_t;
typedef __bf16 bf16x8 __attribute__((ext_vector_type(8)));
typedef float f32x4 __attribute__((ext_vector_type(4)));
typedef unsigned short u16;
typedef u16 u16x8 __attribute__((ext_vector_type(8)));
typedef u16 u16x4 __attribute__((ext_vector_type(4)));

#define AS1 __attribute__((address_space(1)))
#define AS3 __attribute__((address_space(3)))

__device__ __forceinline__ u16 f2bf(float f) {
    uint32_t u = __builtin_bit_cast(uint32_t, f);
    u += 0x7FFFu + ((u >> 16) & 1u);   // round-to-nearest-even
    return (u16)(u >> 16);
}
__device__ __forceinline__ float bf2f(u16 h) {
    return __builtin_bit_cast(float, (uint32_t)h << 16);
}

// ---------------------------------------------------------------- converts
__global__ void k_f32_to_bf16(const float* __restrict__ in, u16* __restrict__ out, int n4) {
    int i = blockIdx.x * blockDim.x + threadIdx.x;
    int stride = gridDim.x * blockDim.x;
    for (; i < n4; i += stride) {
        float4 v = ((const float4*)in)[i];
        ushort4 o;
        o.x = f2bf(v.x); o.y = f2bf(v.y); o.z = f2bf(v.z); o.w = f2bf(v.w);
        ((ushort4*)out)[i] = o;
    }
}

// ---------------------------------------------------------------- GEMM (C = A * B^T), A:MxK bf16, B:NxK bf16
// OUTMODE: 0 = bf16 MxN, 1 = f32 MxN, 2 = bf16 written as V^T (b,h,d,s) for attention
template <int OUTMODE>
__global__ __launch_bounds__(256) void k_gemm_bt(
    const u16* __restrict__ A, const u16* __restrict__ Bm,
    void* __restrict__ C, int M, int N, int K)
{
    __shared__ u16 lA[128 * 32];
    __shared__ u16 lB[128 * 32];

    const int t = threadIdx.x;
    const int lane = t & 63;
    const int wave = t >> 6;
    const int wr = wave >> 1, wc = wave & 1;     // 2x2 waves -> 64x64 each
    const int bm = blockIdx.y * 128, bn = blockIdx.x * 128;

    const int srow = t >> 2;
    const int scol = (t & 3) * 8;
    const size_t a0 = (size_t)(bm + srow) * K + scol;
    const size_t a1 = (size_t)(bm + 64 + srow) * K + scol;
    const size_t b0 = (size_t)(bn + srow) * K + scol;
    const size_t b1 = (size_t)(bn + 64 + srow) * K + scol;

    const int fr = lane & 15;
    const int fk = (lane >> 4) * 8;

    f32x4 acc[4][4];
    const f32x4 fzero = {0.f, 0.f, 0.f, 0.f};
#pragma unroll
    for (int i = 0; i < 4; ++i)
#pragma unroll
        for (int j = 0; j < 4; ++j) acc[i][j] = fzero;

    u16* ldsA = lA + wave * 512;
    u16* ldsB = lB + wave * 512;

    for (int k0 = 0; k0 < K; k0 += 32) {
        __builtin_amdgcn_global_load_lds(
            (const AS1 void*)(A + a0 + k0), (AS3 void*)(ldsA), 16, 0, 0);
        __builtin_amdgcn_global_load_lds(
            (const AS1 void*)(A + a1 + k0), (AS3 void*)(ldsA + 2048), 16, 0, 0);
        __builtin_amdgcn_global_load_lds(
            (const AS1 void*)(Bm + b0 + k0), (AS3 void*)(ldsB), 16, 0, 0);
        __builtin_amdgcn_global_load_lds(
            (const AS1 void*)(Bm + b1 + k0), (AS3 void*)(ldsB + 2048), 16, 0, 0);
        __syncthreads();

        bf16x8 af[4], bfv[4];
#pragma unroll
        for (int mi = 0; mi < 4; ++mi)
            af[mi] = *(const bf16x8*)&lA[(wr * 64 + mi * 16 + fr) * 32 + fk];
#pragma unroll
        for (int ni = 0; ni < 4; ++ni)
            bfv[ni] = *(const bf16x8*)&lB[(wc * 64 + ni * 16 + fr) * 32 + fk];
#pragma unroll
        for (int mi = 0; mi < 4; ++mi)
#pragma unroll
            for (int ni = 0; ni < 4; ++ni)
                acc[mi][ni] = __builtin_amdgcn_mfma_f32_16x16x32_bf16(
                    af[mi], bfv[ni], acc[mi][ni], 0, 0, 0);
        __syncthreads();
    }

    const int cr = (lane >> 4) * 4;
    const int cc = lane & 15;
#pragma unroll
    for (int mi = 0; mi < 4; ++mi) {
#pragma unroll
        for (int ni = 0; ni < 4; ++ni) {
            const int row = bm + wr * 64 + mi * 16 + cr;
            const int col = bn + wc * 64 + ni * 16 + cc;
            if constexpr (OUTMODE == 2) {
                const int b = row >> 11, s0 = row & 2047;
                const int h = col >> 7, d = col & 127;
                u16x4 pk;
#pragma unroll
                for (int r = 0; r < 4; ++r) pk[r] = f2bf(acc[mi][ni][r]);
                *(u16x4*)((u16*)C + ((size_t)((b * 16 + h) * 128 + d)) * 2048 + s0) = pk;
            } else {
#pragma unroll
                for (int r = 0; r < 4; ++r) {
                    float val = acc[mi][ni][r];
                    size_t idx = (size_t)(row + r) * N + col;
                    if constexpr (OUTMODE == 0) ((u16*)C)[idx] = f2bf(val);
                    else                        ((float*)C)[idx] = val;
                }
            }
        }
    }
}

// ---------------------------------------------------------------- RoPE in place on (B*S, H*128) bf16
__global__ void k_rope(u16* __restrict__ x, int S, int n) {
    int i = blockIdx.x * blockDim.x + threadIdx.x;
    if (i >= n) return;
    const int j = i & 63;
    const int h = (i >> 6) & 15;
    const int row = i >> 10;
    const int s = row & (S - 1);
    const float L2B = 13.287712379549449f;
    float inv = exp2f(-(float)(2 * j) * (L2B / 128.f));
    float ang = (float)s * inv;
    float c, sn;
    sincosf(ang, &sn, &c);
    size_t base = (size_t)row * 2048 + h * 128 + j;
    float x1 = bf2f(x[base]);
    float x2 = bf2f(x[base + 64]);
    x[base]      = f2bf(x1 * c - x2 * sn);
    x[base + 64] = f2bf(x2 * c + x1 * sn);
}

// ---------------------------------------------------------------- MFMA flash attention (causal)
// 4 waves/block, wave owns 32 q-rows. KB=32, double-buffered K+V staging (T3 2-phase),
// log2-domain softmax w/ defer-max, per-lane partial l.
// K LDS [2][32][128] chunk-swizzle c16^=kv&7; V^T LDS [2][128][32] chunk-swizzle c^=d&3;
// P per-wave [32][40] u16 (80B rows, 16B-aligned).
__global__ __launch_bounds__(256, 3) void k_flash_mfma(
    const u16* __restrict__ Q, const u16* __restrict__ K, const u16* __restrict__ VT,
    u16* __restrict__ O)
{
    constexpr int S = 2048, H = 16, HD = 2048;
    __shared__ __align__(16) u16 Kt[2][32 * 128];
    __shared__ __align__(16) u16 Vt[2][128 * 32];
    __shared__ __align__(16) u16 Pl[4][32 * 40];

    const int t = threadIdx.x;
    const int lane = t & 63;
    const int w = t >> 6;
    // load balance: pair heavy (b=0) with light (b=1) qt on the same CU; heavy first
    const int b = blockIdx.z;
    const int qt = b ? blockIdx.x : (gridDim.x - 1 - blockIdx.x);
    const int h = blockIdx.y;
    const int q0 = qt * 128;
    const int wq0 = q0 + w * 32;

    const u16* qg = Q + ((size_t)b * S) * HD + h * 128;
    const u16* kg = K + ((size_t)b * S) * HD + h * 128;
    const u16* vg = VT + ((size_t)(b * H + h)) * 128 * S;

    const int r16 = lane & 15;
    const int g4 = lane >> 4;

    // Q fragments, pre-scaled by (1/sqrt(128)) * log2(e)  -> log2-domain scores
    const float scale = 0.08838834764831845f * 1.4426950408889634f;
    bf16x8 aQ[2][4];
#pragma unroll
    for (int qi = 0; qi < 2; ++qi) {
        const u16* qr = qg + (size_t)(wq0 + qi * 16 + r16) * HD;
#pragma unroll
        for (int dk = 0; dk < 4; ++dk) {
            u16x8 u = *(const u16x8*)(qr + dk * 32 + g4 * 8);
            u16x8 uu;
#pragma unroll
            for (int j = 0; j < 8; ++j) uu[j] = f2bf(bf2f(u[j]) * scale);
            aQ[qi][dk] = __builtin_bit_cast(bf16x8, uu);
        }
    }

    f32x4 oa[2][8];
    f32x4 mM[2], lP[2];
    const f32x4 fzero = {0.f, 0.f, 0.f, 0.f};
#pragma unroll
    for (int qi = 0; qi < 2; ++qi) {
        mM[qi] = f32x4{-1e30f, -1e30f, -1e30f, -1e30f};
        lP[qi] = fzero;
#pragma unroll
        for (int dj = 0; dj < 8; ++dj) oa[qi][dj] = fzero;
    }

    // stage one KV tile (K: 8KB, V^T: 8KB) into buffer `buf`
    auto stage = [&](int buf, int j0) {
#pragma unroll
        for (int p = 0; p < 2; ++p) {
            const int off = p * 4096 + w * 1024 + lane * 16;
            const int kv = off >> 8, c16 = (off >> 4) & 15;
            const u16* srcK = kg + (size_t)(j0 + kv) * HD + ((c16 ^ (kv & 7)) * 8);
            __builtin_amdgcn_global_load_lds(
                (const AS1 void*)srcK,
                (AS3 void*)((char*)&Kt[buf][0] + p * 4096 + w * 1024), 16, 0, 0);
            const int d = off >> 6, c = (off >> 4) & 3;
            const u16* srcV = vg + (size_t)d * S + j0 + ((c ^ (d & 3)) * 8);
            __builtin_amdgcn_global_load_lds(
                (const AS1 void*)srcV,
                (AS3 void*)((char*)&Vt[buf][0] + p * 4096 + w * 1024), 16, 0, 0);
        }
    };

    const int nt = 4 * qt + 4;          // tiles this block stages
    const int myLast = 4 * qt + w;      // last tile this wave computes (== diagonal tile)

    stage(0, 0);
    __syncthreads();

    for (int tix = 0; tix < nt; ++tix) {
        const int cur = tix & 1;
        if (tix + 1 < nt) stage(cur ^ 1, (tix + 1) * 32);

        if (tix <= myLast) {
            const u16* Kc = &Kt[cur][0];
            const u16* Vc = &Vt[cur][0];

            // ---- QK^T : 32q x 32kv
            f32x4 sc[2][2];
#pragma unroll
            for (int qi = 0; qi < 2; ++qi) { sc[qi][0] = fzero; sc[qi][1] = fzero; }

#pragma unroll
            for (int dk = 0; dk < 4; ++dk) {
                bf16x8 bK[2];
#pragma unroll
                for (int kf = 0; kf < 2; ++kf) {
                    const int kv = kf * 16 + r16;
                    const int c16 = dk * 4 + g4;
                    bK[kf] = *(const bf16x8*)(Kc + kv * 128 + ((c16 ^ (kv & 7)) * 8));
                }
#pragma unroll
                for (int qi = 0; qi < 2; ++qi)
#pragma unroll
                    for (int kf = 0; kf < 2; ++kf)
                        sc[qi][kf] = __builtin_amdgcn_mfma_f32_16x16x32_bf16(
                            aQ[qi][dk], bK[kf], sc[qi][kf], 0, 0, 0);
            }

            // ---- causal mask, only on the diagonal tile
            if (tix == myLast) {
#pragma unroll
                for (int qi = 0; qi < 2; ++qi)
#pragma unroll
                    for (int kf = 0; kf < 2; ++kf)
#pragma unroll
                        for (int r = 0; r < 4; ++r) {
                            const int lr = qi * 16 + g4 * 4 + r;
                            const int lc = kf * 16 + r16;
                            if (lc > lr) sc[qi][kf][r] = -1e30f;
                        }
            }

            // ---- online softmax (log2 domain, defer-max, per-lane partial l)
#pragma unroll
            for (int qi = 0; qi < 2; ++qi) {
                f32x4 rm;
#pragma unroll
                for (int r = 0; r < 4; ++r) rm[r] = fmaxf(sc[qi][0][r], sc[qi][1][r]);
#pragma unroll
                for (int r = 0; r < 4; ++r) {
                    float v = rm[r];
                    v = fmaxf(v, __shfl_xor(v, 1));
                    v = fmaxf(v, __shfl_xor(v, 2));
                    v = fmaxf(v, __shfl_xor(v, 4));
                    v = fmaxf(v, __shfl_xor(v, 8));
                    rm[r] = v;
                }
                float al[4];
                bool need = false;
#pragma unroll
                for (int r = 0; r < 4; ++r) {
                    if (rm[r] > mM[qi][r] + 8.f) {
                        al[r] = exp2f(mM[qi][r] - rm[r]);
                        mM[qi][r] = rm[r];
                        need = true;
                    } else al[r] = 1.f;
                }
                if (need) {
#pragma unroll
                    for (int dj = 0; dj < 8; ++dj)
#pragma unroll
                        for (int r = 0; r < 4; ++r) oa[qi][dj][r] *= al[r];
#pragma unroll
                    for (int r = 0; r < 4; ++r) lP[qi][r] *= al[r];
                }
#pragma unroll
                for (int kf = 0; kf < 2; ++kf)
#pragma unroll
                    for (int r = 0; r < 4; ++r) {
                        float pp = exp2f(sc[qi][kf][r] - mM[qi][r]);
                        sc[qi][kf][r] = pp;
                        lP[qi][r] += pp;
                    }
                // P -> per-wave LDS (bf16), row q, col kv
#pragma unroll
                for (int kf = 0; kf < 2; ++kf)
#pragma unroll
                    for (int r = 0; r < 4; ++r)
                        Pl[w][(qi * 16 + g4 * 4 + r) * 40 + kf * 16 + r16] = f2bf(sc[qi][kf][r]);
            }

            // ---- PV : O += P @ V  (A = P rows q, k = kv; B = V^T rows d)
            bf16x8 pa[2];
#pragma unroll
            for (int qi = 0; qi < 2; ++qi)
                pa[qi] = *(const bf16x8*)&Pl[w][(qi * 16 + r16) * 40 + g4 * 8];
#pragma unroll
            for (int half = 0; half < 2; ++half) {
                bf16x8 bV[4];
#pragma unroll
                for (int j = 0; j < 4; ++j) {
                    const int d = (half * 4 + j) * 16 + r16;
                    bV[j] = *(const bf16x8*)(Vc + d * 32 + ((g4 ^ (d & 3)) * 8));
                }
#pragma unroll
                for (int qi = 0; qi < 2; ++qi)
#pragma unroll
                    for (int j = 0; j < 4; ++j)
                        oa[qi][half * 4 + j] = __builtin_amdgcn_mfma_f32_16x16x32_bf16(
                            pa[qi], bV[j], oa[qi][half * 4 + j], 0, 0, 0);
            }
        }
        __syncthreads();
    }

    // ---- epilogue: reduce per-lane partial l across the 16-lane row group, write O
#pragma unroll
    for (int qi = 0; qi < 2; ++qi) {
        f32x4 inv;
#pragma unroll
        for (int r = 0; r < 4; ++r) {
            float v = lP[qi][r];
            v += __shfl_xor(v, 1);
            v += __shfl_xor(v, 2);
            v += __shfl_xor(v, 4);
            v += __shfl_xor(v, 8);
            inv[r] = 1.f / v;
        }
#pragma unroll
        for (int r = 0; r < 4; ++r) {
            u16* orow = O + (size_t)(b * S + wq0 + qi * 16 + g4 * 4 + r) * HD + h * 128;
#pragma unroll
            for (int dj = 0; dj < 8; ++dj)
                orow[dj * 16 + r16] = f2bf(oa[qi][dj][r] * inv[r]);
        }
    }
}

// ---------------------------------------------------------------- launch
extern "C" void kernel_launch(void* const* d_in, const int* in_sizes, int n_in,
                              void* d_out, int out_size, void* d_ws, size_t ws_size,
                              hipStream_t stream) {
    const float* hs = (const float*)d_in[0];
    const float* Wq = (const float*)d_in[1];
    const float* Wc = (const float*)d_in[2];
    const float* Wk = (const float*)d_in[3];
    const float* Wv = (const float*)d_in[4];
    const float* Wo = (const float*)d_in[5];

    const int B = 2, S = 2048, D = 2048, DL = 512, H = 16;
    const int M = B * S;   // 4096

    char* p = (char*)d_ws;
    u16* hs_bf = (u16*)p; p += (size_t)M * D * 2;
    u16* Wq_bf = (u16*)p; p += (size_t)D * D * 2;
    u16* Wc_bf = (u16*)p; p += (size_t)DL * D * 2;
    u16* Wk_bf = (u16*)p; p += (size_t)D * DL * 2;
    u16* Wv_bf = (u16*)p; p += (size_t)D * DL * 2;
    u16* Wo_bf = (u16*)p; p += (size_t)D * D * 2;
    u16* qb    = (u16*)p; p += (size_t)M * D * 2;
    u16* kb    = (u16*)p; p += (size_t)M * D * 2;
    u16* vbT   = (u16*)p; p += (size_t)M * D * 2;   // (B,H,128,S)
    u16* ckv   = (u16*)p; p += (size_t)M * DL * 2;
    u16* attn  = (u16*)p; p += (size_t)M * D * 2;

    auto conv = [&](const float* in, u16* out, size_t n) {
        int n4 = (int)(n / 4);
        int blocks = (n4 + 255) / 256;
        if (blocks > 4096) blocks = 4096;
        k_f32_to_bf16<<<blocks, 256, 0, stream>>>(in, out, n4);
    };
    conv(hs, hs_bf, (size_t)M * D);
    conv(Wq, Wq_bf, (size_t)D * D);
    conv(Wc, Wc_bf, (size_t)DL * D);
    conv(Wk, Wk_bf, (size_t)D * DL);
    conv(Wv, Wv_bf, (size_t)D * DL);
    conv(Wo, Wo_bf, (size_t)D * D);

    // q = hs @ Wq^T
    k_gemm_bt<0><<<dim3(D / 128, M / 128), 256, 0, stream>>>(hs_bf, Wq_bf, qb, M, D, D);
    // c_kv = hs @ Wc^T
    k_gemm_bt<0><<<dim3(DL / 128, M / 128), 256, 0, stream>>>(hs_bf, Wc_bf, ckv, M, DL, D);
    // k = c_kv @ Wk^T
    k_gemm_bt<0><<<dim3(D / 128, M / 128), 256, 0, stream>>>(ckv, Wk_bf, kb, M, D, DL);
    // v = c_kv @ Wv^T, written directly as V^T (b,h,d,s)
    k_gemm_bt<2><<<dim3(D / 128, M / 128), 256, 0, stream>>>(ckv, Wv_bf, vbT, M, D, DL);

    {
        int n = M * H * 64;
        int blocks = (n + 255) / 256;
        k_rope<<<blocks, 256, 0, stream>>>(qb, S, n);
        k_rope<<<blocks, 256, 0, stream>>>(kb, S, n);
    }

    k_flash_mfma<<<dim3(S / 128, H, B), 256, 0, stream>>>(qb, kb, vbT, attn);

    // out = attn @ Wo^T  (fp32 out)
    k_gemm_bt<1><<<dim3(D / 128, M / 128), 256, 0, stream>>>(attn, Wo_bf, (float*)d_out, M, D, D);
}

// Round 4
// 358.365 us; speedup vs baseline: 1.1480x; 1.1480x over previous
//
#include <hip/hip_runtime.h>
#include <hip/hip_bf16.h>
#include <stdint.h>
#include <math.h>

typedef __bf16 bf16_t;
typedef __bf16 bf16x8 __attribute__((ext_vector_type(8)));
typedef float f32x4 __attribute__((ext_vector_type(4)));
typedef unsigned short u16;
typedef u16 u16x8 __attribute__((ext_vector_type(8)));
typedef u16 u16x4 __attribute__((ext_vector_type(4)));

#define AS1 __attribute__((address_space(1)))
#define AS3 __attribute__((address_space(3)))

__device__ __forceinline__ u16 f2bf(float f) {
    uint32_t u = __builtin_bit_cast(uint32_t, f);
    u += 0x7FFFu + ((u >> 16) & 1u);   // round-to-nearest-even
    return (u16)(u >> 16);
}
__device__ __forceinline__ float bf2f(u16 h) {
    return __builtin_bit_cast(float, (uint32_t)h << 16);
}

// ---------------------------------------------------------------- converts
__global__ void k_f32_to_bf16(const float* __restrict__ in, u16* __restrict__ out, int n4) {
    int i = blockIdx.x * blockDim.x + threadIdx.x;
    int stride = gridDim.x * blockDim.x;
    for (; i < n4; i += stride) {
        float4 v = ((const float4*)in)[i];
        ushort4 o;
        o.x = f2bf(v.x); o.y = f2bf(v.y); o.z = f2bf(v.z); o.w = f2bf(v.w);
        ((ushort4*)out)[i] = o;
    }
}

// ---------------------------------------------------------------- GEMM (C = A * B^T), A:MxK bf16, B:NxK bf16
// OUTMODE: 0 = bf16 MxN, 1 = f32 MxN, 2 = bf16 written as V^T (b,h,d,s) for attention
template <int OUTMODE>
__global__ __launch_bounds__(256) void k_gemm_bt(
    const u16* __restrict__ A, const u16* __restrict__ Bm,
    void* __restrict__ C, int M, int N, int K)
{
    __shared__ u16 lA[128 * 32];
    __shared__ u16 lB[128 * 32];

    const int t = threadIdx.x;
    const int lane = t & 63;
    const int wave = t >> 6;
    const int wr = wave >> 1, wc = wave & 1;     // 2x2 waves -> 64x64 each

    // T1: bijective XCD-chunked swizzle (all our grids have nwg % 8 == 0)
    const int nwg = gridDim.x * gridDim.y;
    const int id = blockIdx.y * gridDim.x + blockIdx.x;
    const int id2 = (id & 7) * (nwg >> 3) + (id >> 3);
    const int bx = id2 % gridDim.x, by = id2 / gridDim.x;
    const int bm = by * 128, bn = bx * 128;

    const int srow = t >> 2;
    const int scol = (t & 3) * 8;
    const size_t a0 = (size_t)(bm + srow) * K + scol;
    const size_t a1 = (size_t)(bm + 64 + srow) * K + scol;
    const size_t b0 = (size_t)(bn + srow) * K + scol;
    const size_t b1 = (size_t)(bn + 64 + srow) * K + scol;

    const int fr = lane & 15;
    const int fk = (lane >> 4) * 8;

    f32x4 acc[4][4];
    const f32x4 fzero = {0.f, 0.f, 0.f, 0.f};
#pragma unroll
    for (int i = 0; i < 4; ++i)
#pragma unroll
        for (int j = 0; j < 4; ++j) acc[i][j] = fzero;

    u16* ldsA = lA + wave * 512;
    u16* ldsB = lB + wave * 512;

    for (int k0 = 0; k0 < K; k0 += 32) {
        __builtin_amdgcn_global_load_lds(
            (const AS1 void*)(A + a0 + k0), (AS3 void*)(ldsA), 16, 0, 0);
        __builtin_amdgcn_global_load_lds(
            (const AS1 void*)(A + a1 + k0), (AS3 void*)(ldsA + 2048), 16, 0, 0);
        __builtin_amdgcn_global_load_lds(
            (const AS1 void*)(Bm + b0 + k0), (AS3 void*)(ldsB), 16, 0, 0);
        __builtin_amdgcn_global_load_lds(
            (const AS1 void*)(Bm + b1 + k0), (AS3 void*)(ldsB + 2048), 16, 0, 0);
        __syncthreads();

        bf16x8 af[4], bfv[4];
#pragma unroll
        for (int mi = 0; mi < 4; ++mi)
            af[mi] = *(const bf16x8*)&lA[(wr * 64 + mi * 16 + fr) * 32 + fk];
#pragma unroll
        for (int ni = 0; ni < 4; ++ni)
            bfv[ni] = *(const bf16x8*)&lB[(wc * 64 + ni * 16 + fr) * 32 + fk];
#pragma unroll
        for (int mi = 0; mi < 4; ++mi)
#pragma unroll
            for (int ni = 0; ni < 4; ++ni)
                acc[mi][ni] = __builtin_amdgcn_mfma_f32_16x16x32_bf16(
                    af[mi], bfv[ni], acc[mi][ni], 0, 0, 0);
        __syncthreads();
    }

    const int cr = (lane >> 4) * 4;
    const int cc = lane & 15;
#pragma unroll
    for (int mi = 0; mi < 4; ++mi) {
#pragma unroll
        for (int ni = 0; ni < 4; ++ni) {
            const int row = bm + wr * 64 + mi * 16 + cr;
            const int col = bn + wc * 64 + ni * 16 + cc;
            if constexpr (OUTMODE == 2) {
                const int b = row >> 11, s0 = row & 2047;
                const int h = col >> 7, d = col & 127;
                u16x4 pk;
#pragma unroll
                for (int r = 0; r < 4; ++r) pk[r] = f2bf(acc[mi][ni][r]);
                *(u16x4*)((u16*)C + ((size_t)((b * 16 + h) * 128 + d)) * 2048 + s0) = pk;
            } else {
#pragma unroll
                for (int r = 0; r < 4; ++r) {
                    float val = acc[mi][ni][r];
                    size_t idx = (size_t)(row + r) * N + col;
                    if constexpr (OUTMODE == 0) ((u16*)C)[idx] = f2bf(val);
                    else                        ((float*)C)[idx] = val;
                }
            }
        }
    }
}

// ---------------------------------------------------------------- RoPE in place on (B*S, H*128) bf16
__global__ void k_rope(u16* __restrict__ x, int S, int n) {
    int i = blockIdx.x * blockDim.x + threadIdx.x;
    if (i >= n) return;
    const int j = i & 63;
    const int h = (i >> 6) & 15;
    const int row = i >> 10;
    const int s = row & (S - 1);
    const float L2B = 13.287712379549449f;
    float inv = exp2f(-(float)(2 * j) * (L2B / 128.f));
    float ang = (float)s * inv;
    float c, sn;
    sincosf(ang, &sn, &c);
    size_t base = (size_t)row * 2048 + h * 128 + j;
    float x1 = bf2f(x[base]);
    float x2 = bf2f(x[base + 64]);
    x[base]      = f2bf(x1 * c - x2 * sn);
    x[base + 64] = f2bf(x2 * c + x1 * sn);
}

// ---------------------------------------------------------------- MFMA flash attention (causal)
// BARRIER-FREE design: no LDS staging of K/V. Each wave loads its MFMA B-fragments
// straight global->VGPR (16B/lane, 64B-contiguous rows); the 16KB K+V tile is
// L1-resident and L2-resident across blocks. Waves fully independent -> pure TLP.
// 4 waves/block, wave owns 32 q-rows. KB=32 per step. Log2-domain online softmax
// with defer-max; per-lane partial l reduced in epilogue. P roundtrips through
// per-wave LDS [32][40] u16 (80B rows; ~2-way conflicts max).
__global__ __launch_bounds__(256, 2) void k_flash_mfma(
    const u16* __restrict__ Q, const u16* __restrict__ K, const u16* __restrict__ VT,
    u16* __restrict__ O)
{
    constexpr int S = 2048, H = 16, HD = 2048;
    __shared__ __align__(16) u16 Pl[4][32 * 40];

    const int t = threadIdx.x;
    const int lane = t & 63;
    const int w = t >> 6;

    // ---- block remap: XCD-chunked (each XCD gets 4 complete (b,h) pairs, all qt)
    //      + intra-chunk pairing: co-resident blocks c and c+32 have qt summing to 15
    const int wg = blockIdx.x;                       // 512 blocks, 1-D
    const int lg = (wg & 7) * 64 + (wg >> 3);        // logical id, chunk = XCD
    const int c  = lg & 63;
    const int half = c >> 5, pr = (c >> 4) & 1, idx = c & 15;
    const int pair = (lg >> 6) * 4 + half * 2 + pr;  // (b,h) index 0..31
    const int qt = half ? idx : 15 - idx;
    const int b = pair >> 4, h = pair & 15;
    const int wq0 = qt * 128 + w * 32;

    const u16* qg = Q + ((size_t)b * S) * HD + h * 128;
    const u16* kg = K + ((size_t)b * S) * HD + h * 128;
    const u16* vg = VT + ((size_t)pair) * 128 * S;

    const int r16 = lane & 15;
    const int g4 = lane >> 4;

    // Q fragments, pre-scaled by (1/sqrt(128)) * log2(e)  -> log2-domain scores
    const float scale = 0.08838834764831845f * 1.4426950408889634f;
    bf16x8 aQ[2][4];
#pragma unroll
    for (int qi = 0; qi < 2; ++qi) {
        const u16* qr = qg + (size_t)(wq0 + qi * 16 + r16) * HD;
#pragma unroll
        for (int dk = 0; dk < 4; ++dk) {
            u16x8 u = *(const u16x8*)(qr + dk * 32 + g4 * 8);
            u16x8 uu;
#pragma unroll
            for (int j = 0; j < 8; ++j) uu[j] = f2bf(bf2f(u[j]) * scale);
            aQ[qi][dk] = __builtin_bit_cast(bf16x8, uu);
        }
    }

    f32x4 oa[2][8];
    f32x4 mM[2], lP[2];
    const f32x4 fzero = {0.f, 0.f, 0.f, 0.f};
#pragma unroll
    for (int qi = 0; qi < 2; ++qi) {
        mM[qi] = f32x4{-1e30f, -1e30f, -1e30f, -1e30f};
        lP[qi] = fzero;
#pragma unroll
        for (int dj = 0; dj < 8; ++dj) oa[qi][dj] = fzero;
    }

    const int ntw = (wq0 >> 5) + 1;      // tiles this wave processes (KB=32)

    for (int tix = 0; tix < ntw; ++tix) {
        const int j0 = tix * 32;

        // ---- K fragments straight from global (rows kv, 16B/lane, 64B/row-contig)
        bf16x8 bK[2][4];
#pragma unroll
        for (int kf = 0; kf < 2; ++kf) {
            const u16* kr = kg + (size_t)(j0 + kf * 16 + r16) * HD + g4 * 8;
#pragma unroll
            for (int dk = 0; dk < 4; ++dk)
                bK[kf][dk] = __builtin_bit_cast(bf16x8, *(const u16x8*)(kr + dk * 32));
        }

        // ---- QK^T : 32q x 32kv
        f32x4 sc[2][2];
#pragma unroll
        for (int qi = 0; qi < 2; ++qi) { sc[qi][0] = fzero; sc[qi][1] = fzero; }
#pragma unroll
        for (int dk = 0; dk < 4; ++dk)
#pragma unroll
            for (int qi = 0; qi < 2; ++qi)
#pragma unroll
                for (int kf = 0; kf < 2; ++kf)
                    sc[qi][kf] = __builtin_amdgcn_mfma_f32_16x16x32_bf16(
                        aQ[qi][dk], bK[kf][dk], sc[qi][kf], 0, 0, 0);

        // ---- V^T fragments (independent of scores; issue early)
        bf16x8 bV[8];
#pragma unroll
        for (int dj = 0; dj < 8; ++dj) {
            const int d = dj * 16 + r16;
            bV[dj] = __builtin_bit_cast(bf16x8,
                *(const u16x8*)(vg + (size_t)d * S + j0 + g4 * 8));
        }

        // ---- causal mask on the diagonal tile (C layout: row=g4*4+r, col=r16)
        if (tix == ntw - 1) {
#pragma unroll
            for (int qi = 0; qi < 2; ++qi)
#pragma unroll
                for (int kf = 0; kf < 2; ++kf)
#pragma unroll
                    for (int r = 0; r < 4; ++r) {
                        const int lr = qi * 16 + g4 * 4 + r;
                        const int lc = kf * 16 + r16;
                        if (lc > lr) sc[qi][kf][r] = -1e30f;
                    }
        }

        // ---- online softmax (log2 domain, defer-max, per-lane partial l)
#pragma unroll
        for (int qi = 0; qi < 2; ++qi) {
            f32x4 rm;
#pragma unroll
            for (int r = 0; r < 4; ++r) rm[r] = fmaxf(sc[qi][0][r], sc[qi][1][r]);
#pragma unroll
            for (int r = 0; r < 4; ++r) {
                float v = rm[r];
                v = fmaxf(v, __shfl_xor(v, 1));
                v = fmaxf(v, __shfl_xor(v, 2));
                v = fmaxf(v, __shfl_xor(v, 4));
                v = fmaxf(v, __shfl_xor(v, 8));
                rm[r] = v;
            }
            float al[4];
            bool need = false;
#pragma unroll
            for (int r = 0; r < 4; ++r) {
                if (rm[r] > mM[qi][r] + 8.f) {
                    al[r] = __builtin_amdgcn_exp2f(mM[qi][r] - rm[r]);
                    mM[qi][r] = rm[r];
                    need = true;
                } else al[r] = 1.f;
            }
            if (__any(need)) {
#pragma unroll
                for (int dj = 0; dj < 8; ++dj)
#pragma unroll
                    for (int r = 0; r < 4; ++r) oa[qi][dj][r] *= al[r];
#pragma unroll
                for (int r = 0; r < 4; ++r) lP[qi][r] *= al[r];
            }
#pragma unroll
            for (int kf = 0; kf < 2; ++kf)
#pragma unroll
                for (int r = 0; r < 4; ++r) {
                    float pp = __builtin_amdgcn_exp2f(sc[qi][kf][r] - mM[qi][r]);
                    sc[qi][kf][r] = pp;
                    lP[qi][r] += pp;
                }
            // P -> per-wave LDS (bf16), row q, col kv
#pragma unroll
            for (int kf = 0; kf < 2; ++kf)
#pragma unroll
                for (int r = 0; r < 4; ++r)
                    Pl[w][(qi * 16 + g4 * 4 + r) * 40 + kf * 16 + r16] = f2bf(sc[qi][kf][r]);
        }

        // ---- PV : O += P @ V  (A = P rows q; B = V^T rows d)
        bf16x8 pa[2];
#pragma unroll
        for (int qi = 0; qi < 2; ++qi)
            pa[qi] = *(const bf16x8*)&Pl[w][(qi * 16 + r16) * 40 + g4 * 8];
#pragma unroll
        for (int dj = 0; dj < 8; ++dj)
#pragma unroll
            for (int qi = 0; qi < 2; ++qi)
                oa[qi][dj] = __builtin_amdgcn_mfma_f32_16x16x32_bf16(
                    pa[qi], bV[dj], oa[qi][dj], 0, 0, 0);
    }

    // ---- epilogue: reduce per-lane partial l across the 16-lane row group, write O
#pragma unroll
    for (int qi = 0; qi < 2; ++qi) {
        f32x4 inv;
#pragma unroll
        for (int r = 0; r < 4; ++r) {
            float v = lP[qi][r];
            v += __shfl_xor(v, 1);
            v += __shfl_xor(v, 2);
            v += __shfl_xor(v, 4);
            v += __shfl_xor(v, 8);
            inv[r] = 1.f / v;
        }
#pragma unroll
        for (int r = 0; r < 4; ++r) {
            u16* orow = O + (size_t)(b * S + wq0 + qi * 16 + g4 * 4 + r) * HD + h * 128;
#pragma unroll
            for (int dj = 0; dj < 8; ++dj)
                orow[dj * 16 + r16] = f2bf(oa[qi][dj][r] * inv[r]);
        }
    }
}

// ---------------------------------------------------------------- launch
extern "C" void kernel_launch(void* const* d_in, const int* in_sizes, int n_in,
                              void* d_out, int out_size, void* d_ws, size_t ws_size,
                              hipStream_t stream) {
    const float* hs = (const float*)d_in[0];
    const float* Wq = (const float*)d_in[1];
    const float* Wc = (const float*)d_in[2];
    const float* Wk = (const float*)d_in[3];
    const float* Wv = (const float*)d_in[4];
    const float* Wo = (const float*)d_in[5];

    const int B = 2, S = 2048, D = 2048, DL = 512, H = 16;
    const int M = B * S;   // 4096

    char* p = (char*)d_ws;
    u16* hs_bf = (u16*)p; p += (size_t)M * D * 2;
    u16* Wq_bf = (u16*)p; p += (size_t)D * D * 2;
    u16* Wc_bf = (u16*)p; p += (size_t)DL * D * 2;
    u16* Wk_bf = (u16*)p; p += (size_t)D * DL * 2;
    u16* Wv_bf = (u16*)p; p += (size_t)D * DL * 2;
    u16* Wo_bf = (u16*)p; p += (size_t)D * D * 2;
    u16* qb    = (u16*)p; p += (size_t)M * D * 2;
    u16* kb    = (u16*)p; p += (size_t)M * D * 2;
    u16* vbT   = (u16*)p; p += (size_t)M * D * 2;   // (B,H,128,S)
    u16* ckv   = (u16*)p; p += (size_t)M * DL * 2;
    u16* attn  = (u16*)p; p += (size_t)M * D * 2;

    auto conv = [&](const float* in, u16* out, size_t n) {
        int n4 = (int)(n / 4);
        int blocks = (n4 + 255) / 256;
        if (blocks > 4096) blocks = 4096;
        k_f32_to_bf16<<<blocks, 256, 0, stream>>>(in, out, n4);
    };
    conv(hs, hs_bf, (size_t)M * D);
    conv(Wq, Wq_bf, (size_t)D * D);
    conv(Wc, Wc_bf, (size_t)DL * D);
    conv(Wk, Wk_bf, (size_t)D * DL);
    conv(Wv, Wv_bf, (size_t)D * DL);
    conv(Wo, Wo_bf, (size_t)D * D);

    // q = hs @ Wq^T
    k_gemm_bt<0><<<dim3(D / 128, M / 128), 256, 0, stream>>>(hs_bf, Wq_bf, qb, M, D, D);
    // c_kv = hs @ Wc^T
    k_gemm_bt<0><<<dim3(DL / 128, M / 128), 256, 0, stream>>>(hs_bf, Wc_bf, ckv, M, DL, D);
    // k = c_kv @ Wk^T
    k_gemm_bt<0><<<dim3(D / 128, M / 128), 256, 0, stream>>>(ckv, Wk_bf, kb, M, D, DL);
    // v = c_kv @ Wv^T, written directly as V^T (b,h,d,s)
    k_gemm_bt<2><<<dim3(D / 128, M / 128), 256, 0, stream>>>(ckv, Wv_bf, vbT, M, D, DL);

    {
        int n = M * H * 64;
        int blocks = (n + 255) / 256;
        k_rope<<<blocks, 256, 0, stream>>>(qb, S, n);
        k_rope<<<blocks, 256, 0, stream>>>(kb, S, n);
    }

    k_flash_mfma<<<512, 256, 0, stream>>>(qb, kb, vbT, attn);

    // out = attn @ Wo^T  (fp32 out)
    k_gemm_bt<1><<<dim3(D / 128, M / 128), 256, 0, stream>>>(attn, Wo_bf, (float*)d_out, M, D, D);
}